// Round 14
// baseline (822.120 us; speedup 1.0000x reference)
//
#include <hip/hip_runtime.h>

// VQ codebook: z_e (16,256,32,32) f32, codebook (8192,256) f32.
// out f32: z_q_st[4194304] | loss[1] | codes[16384].
// n = b*1024+hw; z_flat[n][d] = z_e[b*262144 + d*1024 + hw]
// Reference: dist = fl32(zz - 2*dot), dot = sequential f32 FMA chain d=0..255,
// argmin ties -> lowest index (validated bitwise in round 2).
//
// Round-14: screen = pure m97-style GEMM (8192 blocks = 128 row-tiles x 64
// code-tiles, 128^2 tile, BK=32, global_load_lds + source XOR swizzle,
// double-buffered LDS, one barrier/K-step) with a per-row TOP-2 epilogue
// (packed score16|code u32), plain uint2 stores, ZERO atomics, fully
// deterministic. Select: gmax = max of stored top1s (every slice max is
// stored); singles = top1 >= tau; slices with top2 >= tau get an exact
// 64-code rescan (covers hidden 3rd+); wave-parallel exact f32 rescore.

#define MRG_C 1.96e-4f   // dot-domain: 1.5*max ulp(zz) + 2*bf16 screen err
#define MRG_SEL 4.6e-4f  // MRG_C + 2*g16 (16-bit key truncation, |s|<0.03)
#define LISTCAP 200

typedef short bf16x8 __attribute__((ext_vector_type(8)));
typedef float f32x16 __attribute__((ext_vector_type(16)));

__device__ __forceinline__ unsigned short f2bf(float f) {
    unsigned u = __float_as_uint(f);
    return (unsigned short)((u + 0x7fffu + ((u >> 16) & 1u)) >> 16);
}
// monotone float<->uint key (total order matches float order)
__device__ __forceinline__ unsigned fkey(float f) {
    unsigned u = __float_as_uint(f);
    return (u & 0x80000000u) ? ~u : (u | 0x80000000u);
}
__device__ __forceinline__ float funkey(unsigned k) {
    unsigned u = (k & 0x80000000u) ? (k ^ 0x80000000u) : ~k;
    return __uint_as_float(u);
}
__device__ __forceinline__ void gload_lds16(const void* g, void* l) {
    __builtin_amdgcn_global_load_lds(
        (const __attribute__((address_space(1))) void*)g,
        (__attribute__((address_space(3))) void*)l, 16, 0, 0);
}

// ---- ws byte layout (big path); WS_NEED == 29,360,128 (r3-proven size) ----
#define PM_B      0u          // uint2[16384][128] = 16 MB (top2 per 64-slice)
#define ZH_B      16777216u   // bf16[16384][256] = 8 MB
#define CH_B      25165824u   // bf16[8192][256] = 4 MB
#define WS_NEED   29360128u

// ---------------- prep: z -> bf16 with transpose ----------------
__global__ __launch_bounds__(256)
void prep_z_kernel(const float* __restrict__ z, unsigned short* __restrict__ zh) {
    __shared__ float zs[64][257];
    const int tid = threadIdx.x;
    const int nbase = blockIdx.x * 64;
    const int b = nbase >> 10, hw0 = nbase & 1023;
    const int lane = tid & 63;
    const int w = tid >> 6;
#pragma unroll 8
    for (int it = 0; it < 64; ++it) {
        int d = it * 4 + w;
        zs[lane][d] = z[(size_t)b * 262144 + (size_t)d * 1024 + hw0 + lane];
    }
    __syncthreads();
#pragma unroll 4
    for (int it = 0; it < 16; ++it) {
        int idx = it * 256 + tid;
        int row = idx >> 6;
        int d4 = idx & 63;
        ushort4 hv;
        hv.x = f2bf(zs[row][d4 * 4 + 0]);
        hv.y = f2bf(zs[row][d4 * 4 + 1]);
        hv.z = f2bf(zs[row][d4 * 4 + 2]);
        hv.w = f2bf(zs[row][d4 * 4 + 3]);
        ((ushort4*)(zh + (size_t)(nbase + row) * 256))[d4] = hv;
    }
}

// ---------------- prep: codebook -> bf16 ----------------
__global__ __launch_bounds__(256)
void split_c_kernel(const float* __restrict__ cb, unsigned short* __restrict__ ch) {
    int gid = blockIdx.x * 256 + threadIdx.x;     // float4 index; 524288 total
    float4 v = ((const float4*)cb)[gid];
    ushort4 hv;
    hv.x = f2bf(v.x); hv.y = f2bf(v.y); hv.z = f2bf(v.z); hv.w = f2bf(v.w);
    ((ushort4*)ch)[gid] = hv;
}

// ---------------- screen GEMM: 128x128 tile, top-2 epilogue ----------------
// grid (128 row-tiles, 64 code-tiles) x 256 thr (4 waves, 2x2).
// K=256 in 8 BK=32 steps; double-buffered 2x16KB LDS (A+B);
// global_load_lds w16 with source XOR granule swizzle ((r^(r>>2))&3).
__global__ __launch_bounds__(256, 2)
void gemm_top2(const unsigned short* __restrict__ zh,
               const unsigned short* __restrict__ ch,
               uint2* __restrict__ pm) {
    __shared__ char smem[32768];   // 2 bufs x (A 8KB @0 + B 8KB @8192)
    const int tid = threadIdx.x;
    const int lane = tid & 63;
    const int wv = tid >> 6;
    const int wm = wv >> 1, wn = wv & 1;
    const int l5 = lane >> 5, l31 = lane & 31;
    const int n0 = blockIdx.x * 128;
    const int c0 = blockIdx.y * 128;

    // staging source offsets (lane-dependent, K-step adds d0).
    // thread t, issue i: LDS byte = i*4096 + t*16 -> row = i*64 + t/4,
    // phys granule p = t&3; source logical granule = p ^ swz(row).
    int srow[2], soff[2];
#pragma unroll
    for (int i = 0; i < 2; ++i) {
        int row = i * 64 + (tid >> 2);
        srow[i] = row;
        soff[i] = ((tid & 3) ^ ((row ^ (row >> 2)) & 3)) * 8;
    }

#define ISSUE(buf, d0)                                                        \
    {                                                                         \
        _Pragma("unroll")                                                     \
        for (int i = 0; i < 2; ++i) {                                         \
            gload_lds16(zh + (size_t)(n0 + srow[i]) * 256 + (d0) + soff[i],   \
                        smem + (buf) * 16384 + i * 4096 + wv * 1024);         \
            gload_lds16(ch + (size_t)(c0 + srow[i]) * 256 + (d0) + soff[i],   \
                        smem + (buf) * 16384 + 8192 + i * 4096 + wv * 1024);  \
        }                                                                     \
    }

    f32x16 acc[2][2];
#pragma unroll
    for (int i = 0; i < 2; ++i)
#pragma unroll
        for (int j = 0; j < 2; ++j)
#pragma unroll
            for (int r = 0; r < 16; ++r) acc[i][j][r] = 0.f;

    const int swl = (l31 ^ (l31 >> 2)) & 3;   // swz(row) for row = C32 + l31
    const int arow0 = (wm * 64 + l31) * 64;
    const int arow1 = (wm * 64 + 32 + l31) * 64;
    const int brow0 = (wn * 64 + l31) * 64;
    const int brow1 = (wn * 64 + 32 + l31) * 64;

    ISSUE(0, 0);   // prologue
    for (int kt = 0; kt < 8; ++kt) {
        __syncthreads();   // drains gloads into buf[kt&1]; prior reads done
        if (kt < 7) ISSUE((kt + 1) & 1, (kt + 1) * 32);
        const char* Ab = smem + (kt & 1) * 16384;
        const char* Bb = Ab + 8192;
#pragma unroll
        for (int ks = 0; ks < 2; ++ks) {
            int go = ((ks * 2 + l5) ^ swl) << 4;
            bf16x8 a0 = *(const bf16x8*)(Ab + arow0 + go);
            bf16x8 a1 = *(const bf16x8*)(Ab + arow1 + go);
            bf16x8 b0 = *(const bf16x8*)(Bb + brow0 + go);
            bf16x8 b1 = *(const bf16x8*)(Bb + brow1 + go);
            acc[0][0] = __builtin_amdgcn_mfma_f32_32x32x16_bf16(a0, b0, acc[0][0], 0, 0, 0);
            acc[0][1] = __builtin_amdgcn_mfma_f32_32x32x16_bf16(a0, b1, acc[0][1], 0, 0, 0);
            acc[1][0] = __builtin_amdgcn_mfma_f32_32x32x16_bf16(a1, b0, acc[1][0], 0, 0, 0);
            acc[1][1] = __builtin_amdgcn_mfma_f32_32x32x16_bf16(a1, b1, acc[1][1], 0, 0, 0);
        }
    }
#undef ISSUE

    // epilogue: per row, top-2 over this wave's 64 codes (2 cq slices),
    // 5-step shfl_xor sorted-pair merge; store uint2 (no atomics).
    const int ctile2 = blockIdx.y * 2 + wn;
#pragma unroll
    for (int rb = 0; rb < 2; ++rb) {
#pragma unroll
        for (int r = 0; r < 16; ++r) {
            unsigned p0 = (fkey(acc[rb][0][r]) & 0xFFFF0000u)
                        | (unsigned)(c0 + wn * 64 + l31);
            unsigned p1 = (fkey(acc[rb][1][r]) & 0xFFFF0000u)
                        | (unsigned)(c0 + wn * 64 + 32 + l31);
            unsigned hi = max(p0, p1), lo = min(p0, p1);
#pragma unroll
            for (int m = 1; m <= 16; m <<= 1) {
                unsigned oh = (unsigned)__shfl_xor((int)hi, m);
                unsigned ol = (unsigned)__shfl_xor((int)lo, m);
                unsigned nh = max(hi, oh);
                unsigned nl = max(min(hi, oh), max(lo, ol));
                hi = nh; lo = nl;
            }
            if (l31 == 0) {
                int gn = n0 + wm * 64 + rb * 32 + 4 * l5 + (r & 3) + 8 * (r >> 2);
                pm[(size_t)gn * 128 + ctile2] = make_uint2(hi, lo);
            }
        }
    }
}

// ---------------- fused select (from top-2 table) + z_q + loss ----------------
__global__ __launch_bounds__(256)
void select_finalize(const float* __restrict__ z, const float* __restrict__ cb,
                     const uint2* __restrict__ pm, float* __restrict__ out) {
    __shared__ float zs[64][257];
    __shared__ unsigned short list_s[4][208];
    __shared__ int codes_s[64];
    __shared__ float wsum[4];
    const int tid = threadIdx.x;
    const int nbase = blockIdx.x * 64;
    const int b = nbase >> 10, hw0 = nbase & 1023;
    const int lane = tid & 63;
    const int w = tid >> 6;

#pragma unroll 8
    for (int it = 0; it < 64; ++it) {
        int d = it * 4 + w;
        zs[lane][d] = z[(size_t)b * 262144 + (size_t)d * 1024 + hw0 + lane];
    }
    __syncthreads();

#pragma unroll 1
    for (int rr = 0; rr < 16; ++rr) {
        const int ridx = w * 16 + rr;
        const int n = nbase + ridx;
        // zz: same sequential chain as reference (bit-exact)
        float zz = 0.f;
        for (int d = 0; d < 256; ++d) {
            float v = zs[ridx][d];
            zz += v * v;
        }
        // lane holds entries 2*lane, 2*lane+1 of pm[n][0..127]
        uint4 e = *(const uint4*)&pm[(size_t)n * 128 + lane * 2];
        unsigned pmax = max(e.x, e.z);
#pragma unroll
        for (int m = 1; m <= 32; m <<= 1)
            pmax = max(pmax, (unsigned)__shfl_xor((int)pmax, m));
        const float tauf = funkey(pmax & 0xFFFF0000u) - MRG_SEL;

        // build candidate code list (compact via ballot+popc)
        int base = 0;
        bool ovf = false;
#pragma unroll
        for (int ee = 0; ee < 2; ++ee) {           // singles: top1 >= tau
            unsigned t1 = ee ? e.z : e.x;
            bool c1 = funkey(t1 & 0xFFFF0000u) >= tauf;
            unsigned long long m1 = __ballot(c1);
            int pos = __popcll(m1 & ((1ull << lane) - 1ull));
            if (c1 && base + pos < LISTCAP)
                list_s[w][base + pos] = (unsigned short)(t1 & 0xFFFFu);
            base += __popcll(m1);
        }
#pragma unroll
        for (int ee = 0; ee < 2; ++ee) {           // flagged slices: top2 >= tau
            unsigned t2 = ee ? e.w : e.y;
            unsigned long long m2 = __ballot(funkey(t2 & 0xFFFF0000u) >= tauf);
            while (m2) {
                int src = __ffsll(m2) - 1;
                m2 &= m2 - 1;
                int half = src * 2 + ee;
                if (base + 64 <= LISTCAP)
                    list_s[w][base + lane] = (unsigned short)(half * 64 + lane);
                else ovf = true;
                base += 64;
            }
        }
        if (base > LISTCAP) ovf = true;

        float bs = 3.0e38f; int bi = 0x7fffffff;
        if (!ovf) {
            for (int c0i = 0; c0i < base; c0i += 64) {
                int idx = c0i + lane;
                if (idx < base) {
                    int k2 = list_s[w][idx];
                    const float* cr = cb + (size_t)k2 * 256;
                    float dot = 0.f;
#pragma unroll 8
                    for (int d4 = 0; d4 < 64; ++d4) {   // exact sequential chain
                        float4 cv = ((const float4*)cr)[d4];
                        dot = fmaf(zs[ridx][d4 * 4 + 0], cv.x, dot);
                        dot = fmaf(zs[ridx][d4 * 4 + 1], cv.y, dot);
                        dot = fmaf(zs[ridx][d4 * 4 + 2], cv.z, dot);
                        dot = fmaf(zs[ridx][d4 * 4 + 3], cv.w, dot);
                    }
                    float sc = zz - 2.0f * dot;   // reference score rounding
                    if (sc < bs || (sc == bs && k2 < bi)) { bs = sc; bi = k2; }
                }
            }
        } else {
            // overflow fallback: exact full scan (P ~ 0)
            for (int base2 = 0; base2 < 8192; base2 += 64) {
                const float* cr = cb + (size_t)(base2 + lane) * 256;
                float dot = 0.f;
#pragma unroll 8
                for (int d4 = 0; d4 < 64; ++d4) {
                    float4 cv = ((const float4*)cr)[d4];
                    dot = fmaf(zs[ridx][d4 * 4 + 0], cv.x, dot);
                    dot = fmaf(zs[ridx][d4 * 4 + 1], cv.y, dot);
                    dot = fmaf(zs[ridx][d4 * 4 + 2], cv.z, dot);
                    dot = fmaf(zs[ridx][d4 * 4 + 3], cv.w, dot);
                }
                float sc = zz - 2.0f * dot;
                int k = base2 + lane;
                if (sc < bs || (sc == bs && k < bi)) { bs = sc; bi = k; }
            }
        }
#pragma unroll
        for (int m = 1; m <= 32; m <<= 1) {
            float ps = __shfl_xor(bs, m);
            int pi = __shfl_xor(bi, m);
            if (ps < bs || (ps == bs && pi < bi)) { bs = ps; bi = pi; }
        }
        if (lane == 0) { codes_s[ridx] = bi; out[4194305 + n] = (float)bi; }
    }
    __syncthreads();

    const int code = codes_s[lane];
    const float* crow = cb + (size_t)code * 256;
    float part = 0.f;
#pragma unroll 8
    for (int j = 0; j < 64; ++j) {
        int d = w * 64 + j;
        float cv = crow[d];
        float ze = zs[lane][d];
        out[(size_t)b * 262144 + (size_t)d * 1024 + hw0 + lane] = cv;
        float diff = ze - cv;
        part += diff * diff;
    }
#pragma unroll
    for (int off = 32; off > 0; off >>= 1) part += __shfl_down(part, off);
    if (lane == 0) wsum[w] = part;
    __syncthreads();
    if (tid == 0) {
        float t = (wsum[0] + wsum[1] + wsum[2] + wsum[3]) * (1.25f / 4194304.f);
        atomicAdd(out + 4194304, t);
    }
}

// ================= fallback path (round-2 kernels, ws-small case) =================
#define NT 128
#define KT 128
#define DC 64
#define KS 4
#define KRANGE (8192 / KS)
#define PSCORE_OFF 32768
#define PIDX_OFF (32768 + KS * 16384)

__global__ __launch_bounds__(256)
void znorm_kernel(const float* __restrict__ z, float* __restrict__ zn) {
    int n = blockIdx.x * 256 + threadIdx.x;
    int b = n >> 10, hw = n & 1023;
    const float* zp = z + (size_t)b * 262144 + hw;
    float s = 0.f;
    for (int d = 0; d < 256; ++d) {
        float v = zp[(size_t)d << 10];
        s += v * v;
    }
    zn[n] = s;
}

__global__ __launch_bounds__(256, 2)
void dist_argmin_kernel(const float* __restrict__ z, const float* __restrict__ cb,
                        const float* __restrict__ zn,
                        float* __restrict__ pscore, int* __restrict__ pidx) {
    __shared__ float zs[DC][NT];
    __shared__ float cs[DC][KT];
    const int tid = threadIdx.x;
    const int tn = tid & 15;
    const int tk = tid >> 4;
    const int n0 = blockIdx.x * NT;
    const int b = n0 >> 10;
    const int hw0 = n0 & 1023;
    const float* zb = z + (size_t)b * 262144 + hw0;
    const int k0base = blockIdx.y * KRANGE;
    float zzr[8];
#pragma unroll
    for (int i = 0; i < 8; ++i) {
        int row = (i < 4) ? (tn * 4 + i) : (64 + tn * 4 + (i - 4));
        zzr[i] = zn[n0 + row];
    }
    float best[8]; int bidx[8];
#pragma unroll
    for (int i = 0; i < 8; ++i) { best[i] = 3.0e38f; bidx[i] = 0; }
    for (int kt = 0; kt < KRANGE / KT; ++kt) {
        const int k0 = k0base + kt * KT;
        float acc[8][8];
#pragma unroll
        for (int i = 0; i < 8; ++i)
#pragma unroll
            for (int j = 0; j < 8; ++j) acc[i][j] = 0.f;
        for (int dc = 0; dc < 256; dc += DC) {
            __syncthreads();
#pragma unroll
            for (int it = 0; it < 8; ++it) {
                int idx = it * 256 + tid;
                int d = idx >> 5, nv = idx & 31;
                float4 v = *(const float4*)(zb + (size_t)(dc + d) * 1024 + nv * 4);
                *(float4*)&zs[d][nv * 4] = v;
            }
#pragma unroll
            for (int it = 0; it < 8; ++it) {
                int idx = it * 256 + tid;
                int k = idx >> 4, dv = idx & 15;
                float4 v = *(const float4*)(cb + (size_t)(k0 + k) * 256 + dc + dv * 4);
                int colv = k ^ ((dv & 7) << 2);
                cs[dv * 4 + 0][colv] = v.x;
                cs[dv * 4 + 1][colv] = v.y;
                cs[dv * 4 + 2][colv] = v.z;
                cs[dv * 4 + 3][colv] = v.w;
            }
            __syncthreads();
#pragma unroll 2
            for (int d = 0; d < DC; ++d) {
                int swz = ((d >> 2) & 7) << 2;
                float4 a0 = *(const float4*)&zs[d][tn * 4];
                float4 a1 = *(const float4*)&zs[d][64 + tn * 4];
                float4 b0 = *(const float4*)&cs[d][(tk * 4) ^ swz];
                float4 b1 = *(const float4*)&cs[d][(64 + tk * 4) ^ swz];
                float av[8] = {a0.x, a0.y, a0.z, a0.w, a1.x, a1.y, a1.z, a1.w};
                float bv[8] = {b0.x, b0.y, b0.z, b0.w, b1.x, b1.y, b1.z, b1.w};
#pragma unroll
                for (int i = 0; i < 8; ++i)
#pragma unroll
                    for (int j = 0; j < 8; ++j)
                        acc[i][j] = fmaf(av[i], bv[j], acc[i][j]);
            }
        }
#pragma unroll
        for (int j = 0; j < 8; ++j) {
            int kloc = (j < 4) ? (tk * 4 + j) : (64 + tk * 4 + (j - 4));
            int kk = k0 + kloc;
#pragma unroll
            for (int i = 0; i < 8; ++i) {
                float s = zzr[i] - 2.0f * acc[i][j];
                if (s < best[i]) { best[i] = s; bidx[i] = kk; }
            }
        }
    }
    __syncthreads();
    float* sredf = &zs[0][0];
    int* sredi = (int*)&cs[0][0];
#pragma unroll
    for (int i = 0; i < 8; ++i) {
        int row = (i < 4) ? (tn * 4 + i) : (64 + tn * 4 + (i - 4));
        sredf[row * 16 + tk] = best[i];
        sredi[row * 16 + tk] = bidx[i];
    }
    __syncthreads();
    if (tid < NT) {
        float bs = sredf[tid * 16];
        int bi = sredi[tid * 16];
#pragma unroll
        for (int t = 1; t < 16; ++t) {
            float s = sredf[tid * 16 + t];
            int ix = sredi[tid * 16 + t];
            if (s < bs || (s == bs && ix < bi)) { bs = s; bi = ix; }
        }
        pscore[blockIdx.y * 16384 + n0 + tid] = bs;
        pidx[blockIdx.y * 16384 + n0 + tid] = bi;
    }
}

__global__ __launch_bounds__(256)
void finalize_kernel(const float* __restrict__ z, const float* __restrict__ cb,
                     const float* __restrict__ pscore, const int* __restrict__ pidx,
                     float* __restrict__ out) {
    __shared__ int codes_s[64];
    __shared__ float wsum[4];
    const int nbase = blockIdx.x * 64;
    const int tid = threadIdx.x;
    if (tid < 64) {
        int n = nbase + tid;
        float bs = pscore[n];
        int bi = pidx[n];
#pragma unroll
        for (int p = 1; p < KS; ++p) {
            float s = pscore[p * 16384 + n];
            int ix = pidx[p * 16384 + n];
            if (s < bs || (s == bs && ix < bi)) { bs = s; bi = ix; }
        }
        codes_s[tid] = bi;
        out[4194305 + n] = (float)bi;
    }
    __syncthreads();
    const int lane = tid & 63;
    const int w = tid >> 6;
    const int n = nbase + lane;
    const int b = n >> 10, hw = n & 1023;
    const int code = codes_s[lane];
    const float* crow = cb + (size_t)code * 256;
    const float* zrow = z + (size_t)b * 262144 + hw;
    float* orow = out + (size_t)b * 262144 + hw;
    float part = 0.f;
    for (int j = 0; j < 64; ++j) {
        int d = w * 64 + j;
        float cv = crow[d];
        float ze = zrow[(size_t)d * 1024];
        orow[(size_t)d * 1024] = cv;
        float diff = ze - cv;
        part += diff * diff;
    }
#pragma unroll
    for (int off = 32; off > 0; off >>= 1) part += __shfl_down(part, off);
    if (lane == 0) wsum[w] = part;
    __syncthreads();
    if (tid == 0) {
        float t = (wsum[0] + wsum[1] + wsum[2] + wsum[3]) * (1.25f / 4194304.f);
        atomicAdd(out + 4194304, t);
    }
}

// ================= launcher =================
extern "C" void kernel_launch(void* const* d_in, const int* in_sizes, int n_in,
                              void* d_out, int out_size, void* d_ws, size_t ws_size,
                              hipStream_t stream) {
    const float* z = (const float*)d_in[0];
    const float* cb = (const float*)d_in[1];
    float* out = (float*)d_out;
    char* wsb = (char*)d_ws;

    if (ws_size >= WS_NEED) {
        uint2* pm = (uint2*)(wsb + PM_B);
        unsigned short* zh = (unsigned short*)(wsb + ZH_B);
        unsigned short* ch = (unsigned short*)(wsb + CH_B);

        hipMemsetAsync(out + 4194304, 0, sizeof(float), stream);
        prep_z_kernel<<<256, 256, 0, stream>>>(z, zh);
        split_c_kernel<<<2048, 256, 0, stream>>>(cb, ch);
        gemm_top2<<<dim3(128, 64), 256, 0, stream>>>(zh, ch, pm);
        select_finalize<<<256, 256, 0, stream>>>(z, cb, pm, out);
    } else {
        float* zn = (float*)wsb;
        float* pscore = (float*)wsb + PSCORE_OFF;
        int* pidx = (int*)((float*)wsb + PIDX_OFF);
        znorm_kernel<<<64, 256, 0, stream>>>(z, zn);
        dim3 grid(16384 / NT, KS);
        dist_argmin_kernel<<<grid, 256, 0, stream>>>(z, cb, zn, pscore, pidx);
        hipMemsetAsync(out + 4194304, 0, sizeof(float), stream);
        finalize_kernel<<<16384 / 64, 256, 0, stream>>>(z, cb, pscore, pidx, out);
    }
}